// Round 2
// baseline (382.963 us; speedup 1.0000x reference)
//
#include <hip/hip_runtime.h>

#define SPB 5   // samples per block
#define TPB 256

// LDS layouts (all 16B-aligned plane bases):
//  x  : bf16 packed pairs, per sample 49 planes x 28 uints (49 bf16 + pad)
//  h1 : bf16 packed pairs, per sample 2 ch x 25 planes x 16 uints (25 bf16 + pad)
//  w1 : fp32, 18 planes x 12 floats (9 + pad)
//  w2 : fp32, 72 planes x 12 floats (9 + pad)

__device__ __forceinline__ unsigned bf16rne(float f) {
    unsigned u = __float_as_uint(f);
    return (u + 0x7fffu + ((u >> 16) & 1u)) >> 16;
}
__device__ __forceinline__ void unpack2(unsigned u, float& a, float& b) {
    a = __uint_as_float(u << 16);
    b = __uint_as_float(u & 0xffff0000u);
}

__global__ __launch_bounds__(TPB, 3)
void conv4d_fused(const float* __restrict__ x,
                  const float* __restrict__ w1, const float* __restrict__ b1,
                  const float* __restrict__ w2, const float* __restrict__ b2,
                  float* __restrict__ out, int B)
{
    __shared__ __align__(16) unsigned s_xu[SPB * 49 * 28];   // 6860 uints
    __shared__ __align__(16) unsigned s_h1[SPB * 2 * 25 * 16]; // 4000 uints
    __shared__ __align__(16) float s_w1[18 * 12];
    __shared__ __align__(16) float s_w2[72 * 12];
    __shared__ float s_b1[2];
    __shared__ float s_b2[4];

    const int t  = threadIdx.x;
    const int s0 = blockIdx.x * SPB;
    const int ns = min(SPB, B - s0);

    // ---- stage weights (padded planes) + biases
    for (int i = t; i < 162; i += TPB) { int p = i / 9, q = i % 9; s_w1[p * 12 + q] = w1[i]; }
    for (int i = t; i < 648; i += TPB) { int p = i / 9, q = i % 9; s_w2[p * 12 + q] = w2[i]; }
    if (t < 2) s_b1[t] = b1[t];
    if (t < 4) s_b2[t] = b2[t];

    // ---- stage x: fp32 global -> packed bf16 LDS, plane-padded
    {
        const int nunits = ns * 49 * 25;   // per plane: 24 pair-units + 1 single
        for (int u = t; u < nunits; u += TPB) {
            int s = u / 1225;
            int r = u % 1225;
            int p = r / 25;
            int j = r % 25;
            const float* gp = x + (size_t)(s0 + s) * 2401 + p * 49;
            unsigned* lp = s_xu + s * 1372 + p * 28;
            if (j < 24) {
                float a = gp[2 * j], b = gp[2 * j + 1];
                lp[j] = bf16rne(a) | (bf16rne(b) << 16);
            } else {
                lp[24] = bf16rne(gp[48]);
            }
        }
    }
    __syncthreads();

    // ---- conv1 + ReLU: task = (o, s, l, d) -> 5x5 plane, 250 tasks
    if (t < 250) {
        int o = t / 125;
        int r = t % 125;
        int s = r / 25;
        int ld = r % 25;
        int l = ld / 5, d = ld % 5;
        if (s < ns) {
            float acc[25];
            const float bias = s_b1[o];
            #pragma unroll
            for (int i = 0; i < 25; ++i) acc[i] = bias;

            const unsigned* xb = s_xu + s * 1372 + (l * 7 + d) * 28;
            const float* wb = s_w1 + o * 108;   // 9 planes * 12

            #pragma unroll
            for (int kl = 0; kl < 3; ++kl)
            #pragma unroll
            for (int kd = 0; kd < 3; ++kd) {
                const unsigned* pp = xb + (kl * 7 + kd) * 28;
                unsigned u[25];
                #pragma unroll
                for (int q4 = 0; q4 < 6; ++q4) {
                    uint4 q = ((const uint4*)pp)[q4];
                    u[q4 * 4 + 0] = q.x; u[q4 * 4 + 1] = q.y;
                    u[q4 * 4 + 2] = q.z; u[q4 * 4 + 3] = q.w;
                }
                u[24] = pp[24];
                float X[49];
                #pragma unroll
                for (int i = 0; i < 24; ++i) unpack2(u[i], X[2 * i], X[2 * i + 1]);
                X[48] = __uint_as_float(u[24] << 16);

                const float* wp = wb + (kl * 3 + kd) * 12;
                float wv[9];
                float4 wq0 = *(const float4*)wp;
                float4 wq1 = *(const float4*)(wp + 4);
                wv[0] = wq0.x; wv[1] = wq0.y; wv[2] = wq0.z; wv[3] = wq0.w;
                wv[4] = wq1.x; wv[5] = wq1.y; wv[6] = wq1.z; wv[7] = wq1.w;
                wv[8] = wp[8];

                #pragma unroll
                for (int kh = 0; kh < 3; ++kh)
                #pragma unroll
                for (int kw = 0; kw < 3; ++kw) {
                    const float wvv = wv[kh * 3 + kw];
                    #pragma unroll
                    for (int h = 0; h < 5; ++h)
                    #pragma unroll
                    for (int w = 0; w < 5; ++w)
                        acc[h * 5 + w] += X[(h + kh) * 7 + (w + kw)] * wvv;
                }
            }

            // ReLU + pack to bf16 pairs + store h1 plane (13 uints)
            unsigned* hp = s_h1 + ((s * 2 + o) * 25 + ld) * 16;
            unsigned pk[12];
            #pragma unroll
            for (int j = 0; j < 12; ++j) {
                float a = fmaxf(acc[2 * j], 0.0f);
                float b = fmaxf(acc[2 * j + 1], 0.0f);
                pk[j] = bf16rne(a) | (bf16rne(b) << 16);
            }
            ((uint4*)hp)[0] = make_uint4(pk[0], pk[1], pk[2], pk[3]);
            ((uint4*)hp)[1] = make_uint4(pk[4], pk[5], pk[6], pk[7]);
            ((uint4*)hp)[2] = make_uint4(pk[8], pk[9], pk[10], pk[11]);
            hp[12] = bf16rne(fmaxf(acc[24], 0.0f));
        }
    }
    __syncthreads();

    // ---- conv2 + ReLU: task = (s, o2, l, d) -> 3x3 plane, 180 tasks
    if (t < 180) {
        int s = t / 36;
        int r = t % 36;
        int o2 = r / 9;
        int ld = r % 9;
        int l = ld / 3, d = ld % 3;
        if (s < ns) {
            float acc[9];
            const float bias = s_b2[o2];
            #pragma unroll
            for (int i = 0; i < 9; ++i) acc[i] = bias;

            #pragma unroll
            for (int c = 0; c < 2; ++c) {
                const unsigned* hb = s_h1 + ((s * 2 + c) * 25 + (l * 5 + d)) * 16;
                const float* wb = s_w2 + ((o2 * 2 + c) * 9) * 12;
                #pragma unroll
                for (int kl = 0; kl < 3; ++kl)
                #pragma unroll
                for (int kd = 0; kd < 3; ++kd) {
                    const unsigned* pp = hb + (kl * 5 + kd) * 16;
                    unsigned u[13];
                    #pragma unroll
                    for (int q4 = 0; q4 < 3; ++q4) {
                        uint4 q = ((const uint4*)pp)[q4];
                        u[q4 * 4 + 0] = q.x; u[q4 * 4 + 1] = q.y;
                        u[q4 * 4 + 2] = q.z; u[q4 * 4 + 3] = q.w;
                    }
                    u[12] = pp[12];
                    float X[25];
                    #pragma unroll
                    for (int i = 0; i < 12; ++i) unpack2(u[i], X[2 * i], X[2 * i + 1]);
                    X[24] = __uint_as_float(u[12] << 16);

                    const float* wp = wb + (kl * 3 + kd) * 12;
                    float wv[9];
                    float4 wq0 = *(const float4*)wp;
                    float4 wq1 = *(const float4*)(wp + 4);
                    wv[0] = wq0.x; wv[1] = wq0.y; wv[2] = wq0.z; wv[3] = wq0.w;
                    wv[4] = wq1.x; wv[5] = wq1.y; wv[6] = wq1.z; wv[7] = wq1.w;
                    wv[8] = wp[8];

                    #pragma unroll
                    for (int kh = 0; kh < 3; ++kh)
                    #pragma unroll
                    for (int kw = 0; kw < 3; ++kw) {
                        const float wvv = wv[kh * 3 + kw];
                        #pragma unroll
                        for (int h = 0; h < 3; ++h)
                        #pragma unroll
                        for (int w = 0; w < 3; ++w)
                            acc[h * 3 + w] += X[(h + kh) * 5 + (w + kw)] * wvv;
                    }
                }
            }
            float* op = out + (size_t)(s0 + s) * 324 + o2 * 81 + l * 27 + d * 9;
            #pragma unroll
            for (int i = 0; i < 9; ++i) op[i] = fmaxf(acc[i], 0.0f);
        }
    }
}

extern "C" void kernel_launch(void* const* d_in, const int* in_sizes, int n_in,
                              void* d_out, int out_size, void* d_ws, size_t ws_size,
                              hipStream_t stream)
{
    const float* x  = (const float*)d_in[0];
    const float* w1 = (const float*)d_in[1];
    const float* b1 = (const float*)d_in[2];
    const float* w2 = (const float*)d_in[3];
    const float* b2 = (const float*)d_in[4];
    float* out = (float*)d_out;

    const int B = in_sizes[0] / 2401;        // 16384
    const int grid = (B + SPB - 1) / SPB;    // 3277 blocks
    conv4d_fused<<<grid, TPB, 0, stream>>>(x, w1, b1, w2, b2, out, B);
}

// Round 3
// 368.589 us; speedup vs baseline: 1.0390x; 1.0390x over previous
//
#include <hip/hip_runtime.h>

#define TPB 256
#define WPB 4   // waves per block; one sample per wave

// Per-wave LDS regions (bank-conflict-free strides):
//  x  : bf16 pairs, 49 planes x 26 uints (25 used)  -> stride 26 (8B-aligned, not 16B)
//  h1 : bf16 pairs, 2ch x 25 planes x 18 uints (13 used) -> stride 18
//  w1 : bf16 pairs, 18 planes x 8 uints (5 used)
//  w2 : bf16 pairs, 72 planes x 8 uints (5 used)

__device__ __forceinline__ unsigned bf16rne(float f) {
    unsigned u = __float_as_uint(f);
    return (u + 0x7fffu + ((u >> 16) & 1u)) >> 16;
}
__device__ __forceinline__ void unpack2(unsigned u, float& a, float& b) {
    a = __uint_as_float(u << 16);
    b = __uint_as_float(u & 0xffff0000u);
}
__device__ __forceinline__ void ldswait() {
    __asm__ volatile("s_waitcnt lgkmcnt(0)" ::: "memory");
}

__global__ __launch_bounds__(TPB, 4)
void conv4d_fused(const float* __restrict__ x,
                  const float* __restrict__ w1, const float* __restrict__ b1,
                  const float* __restrict__ w2, const float* __restrict__ b2,
                  float* __restrict__ out, int B)
{
    __shared__ __align__(16) unsigned s_xu[WPB * 49 * 26];   // 5096 uints
    __shared__ __align__(16) unsigned s_h1[WPB * 2 * 25 * 18]; // 3600 uints
    __shared__ __align__(16) unsigned s_w1u[18 * 8];
    __shared__ __align__(16) unsigned s_w2u[72 * 8];

    const int t    = threadIdx.x;
    const int lane = t & 63;
    const int wid  = t >> 6;
    const int s    = blockIdx.x * WPB + wid;

    // ---- weights: every wave writes identical values (idempotent, no barrier)
    for (int i = lane; i < 90; i += 64) {
        int p = i / 5, q = i - p * 5;
        int base = p * 9 + q * 2;
        float a = w1[base];
        float b = (q < 4) ? w1[min(base + 1, 161)] : 0.0f;
        s_w1u[p * 8 + q] = (q < 4) ? (bf16rne(a) | (bf16rne(b) << 16)) : bf16rne(a);
    }
    for (int i = lane; i < 360; i += 64) {
        int p = i / 5, q = i - p * 5;
        int base = p * 9 + q * 2;
        float a = w2[base];
        float b = (q < 4) ? w2[min(base + 1, 647)] : 0.0f;
        s_w2u[p * 8 + q] = (q < 4) ? (bf16rne(a) | (bf16rne(b) << 16)) : bf16rne(a);
    }

    // ---- stage x for this wave's sample (fp32 global -> packed bf16 LDS)
    if (s < B) {
        const float* gx = x + (size_t)s * 2401;
        unsigned* xw = s_xu + wid * 1274;
        for (int u = lane; u < 1225; u += 64) {
            int p = u / 25, j = u - p * 25;
            const float* gp = gx + p * 49;
            float a = gp[min(2 * j, 48)];
            float b = (j < 24) ? gp[min(2 * j + 1, 48)] : 0.0f;
            xw[p * 26 + j] = (j < 24) ? (bf16rne(a) | (bf16rne(b) << 16)) : bf16rne(a);
        }
    }
    ldswait();

    // ---- conv1 + ReLU: 50 tasks (o, l, d), each a 5x5 plane
    if (s < B && lane < 50) {
        const int o = (lane >= 25) ? 1 : 0;
        const int r = lane - o * 25;
        const int l = r / 5, d = r - (r / 5) * 5;

        float acc[25];
        const float bias = b1[o];
        #pragma unroll
        for (int i = 0; i < 25; ++i) acc[i] = bias;

        const unsigned* xb = s_xu + wid * 1274 + (l * 7 + d) * 26;
        const unsigned* wb = s_w1u + o * 72;

        #pragma unroll
        for (int kl = 0; kl < 3; ++kl)
        #pragma unroll
        for (int kd = 0; kd < 3; ++kd) {
            const unsigned* pp = xb + (kl * 7 + kd) * 26;
            unsigned u[25];
            #pragma unroll
            for (int k = 0; k < 12; ++k) {
                uint2 q = ((const uint2*)pp)[k];
                u[2 * k] = q.x; u[2 * k + 1] = q.y;
            }
            u[24] = pp[24];
            float X[49];
            #pragma unroll
            for (int k = 0; k < 24; ++k) unpack2(u[k], X[2 * k], X[2 * k + 1]);
            X[48] = __uint_as_float(u[24] << 16);

            const unsigned* wp = wb + (kl * 3 + kd) * 8;
            uint4 wq = *(const uint4*)wp;
            unsigned w8u = wp[4];
            float wv[9];
            unpack2(wq.x, wv[0], wv[1]);
            unpack2(wq.y, wv[2], wv[3]);
            unpack2(wq.z, wv[4], wv[5]);
            unpack2(wq.w, wv[6], wv[7]);
            wv[8] = __uint_as_float(w8u << 16);

            #pragma unroll
            for (int kh = 0; kh < 3; ++kh)
            #pragma unroll
            for (int kw = 0; kw < 3; ++kw) {
                const float wvv = wv[kh * 3 + kw];
                #pragma unroll
                for (int h = 0; h < 5; ++h)
                #pragma unroll
                for (int w = 0; w < 5; ++w)
                    acc[h * 5 + w] += X[(h + kh) * 7 + (w + kw)] * wvv;
            }
        }

        // ReLU + pack + store h1 plane (13 uints at stride-18 plane)
        unsigned* hp = s_h1 + wid * 900 + (o * 25 + r) * 18;
        unsigned pk[12];
        #pragma unroll
        for (int j = 0; j < 12; ++j) {
            float a = fmaxf(acc[2 * j], 0.0f);
            float b = fmaxf(acc[2 * j + 1], 0.0f);
            pk[j] = bf16rne(a) | (bf16rne(b) << 16);
        }
        #pragma unroll
        for (int k = 0; k < 6; ++k)
            ((uint2*)hp)[k] = make_uint2(pk[2 * k], pk[2 * k + 1]);
        hp[12] = bf16rne(fmaxf(acc[24], 0.0f));
    }
    ldswait();

    // ---- conv2 + ReLU: 36 tasks (o2, l, d), each a 3x3 plane
    if (s < B && lane < 36) {
        const int o2 = lane / 9;
        const int r  = lane - o2 * 9;
        const int l = r / 3, d = r - (r / 3) * 3;

        float acc[9];
        const float bias = b2[o2];
        #pragma unroll
        for (int i = 0; i < 9; ++i) acc[i] = bias;

        #pragma unroll
        for (int c = 0; c < 2; ++c) {
            #pragma unroll
            for (int kl = 0; kl < 3; ++kl)
            #pragma unroll
            for (int kd = 0; kd < 3; ++kd) {
                const unsigned* pp = s_h1 + wid * 900
                                   + (c * 25 + (l + kl) * 5 + (d + kd)) * 18;
                unsigned u[13];
                #pragma unroll
                for (int k = 0; k < 6; ++k) {
                    uint2 q = ((const uint2*)pp)[k];
                    u[2 * k] = q.x; u[2 * k + 1] = q.y;
                }
                u[12] = pp[12];
                float X[25];
                #pragma unroll
                for (int k = 0; k < 12; ++k) unpack2(u[k], X[2 * k], X[2 * k + 1]);
                X[24] = __uint_as_float(u[12] << 16);

                const unsigned* wp = s_w2u + ((o2 * 2 + c) * 9 + kl * 3 + kd) * 8;
                uint4 wq = *(const uint4*)wp;
                unsigned w8u = wp[4];
                float wv[9];
                unpack2(wq.x, wv[0], wv[1]);
                unpack2(wq.y, wv[2], wv[3]);
                unpack2(wq.z, wv[4], wv[5]);
                unpack2(wq.w, wv[6], wv[7]);
                wv[8] = __uint_as_float(w8u << 16);

                #pragma unroll
                for (int kh = 0; kh < 3; ++kh)
                #pragma unroll
                for (int kw = 0; kw < 3; ++kw) {
                    const float wvv = wv[kh * 3 + kw];
                    #pragma unroll
                    for (int h = 0; h < 3; ++h)
                    #pragma unroll
                    for (int w = 0; w < 3; ++w)
                        acc[h * 3 + w] += X[(h + kh) * 5 + (w + kw)] * wvv;
                }
            }
        }
        float* op = out + (size_t)s * 324 + lane * 9;   // lane*9 == o2*81 + r*9
        #pragma unroll
        for (int i = 0; i < 9; ++i) op[i] = fmaxf(acc[i], 0.0f);
    }
}

extern "C" void kernel_launch(void* const* d_in, const int* in_sizes, int n_in,
                              void* d_out, int out_size, void* d_ws, size_t ws_size,
                              hipStream_t stream)
{
    const float* x  = (const float*)d_in[0];
    const float* w1 = (const float*)d_in[1];
    const float* b1 = (const float*)d_in[2];
    const float* w2 = (const float*)d_in[3];
    const float* b2 = (const float*)d_in[4];
    float* out = (float*)d_out;

    const int B = in_sizes[0] / 2401;          // 16384
    const int grid = (B + WPB - 1) / WPB;      // 4096 blocks
    conv4d_fused<<<grid, TPB, 0, stream>>>(x, w1, b1, w2, b2, out, B);
}